// Round 2
// baseline (318.312 us; speedup 1.0000x reference)
//
#include <hip/hip_runtime.h>
#include <math.h>

#define HH 240
#define WW 240
#define PP (HH * WW)
#define PW 242              // padded height/width for conv input
#define LOG_MAX_C 4.605170185988091f  // log(100)
#define LOG2E 1.442695040888963f

typedef __bf16 bf16x8 __attribute__((ext_vector_type(8)));
typedef float  f32x4  __attribute__((ext_vector_type(4)));
typedef float  f32x16 __attribute__((ext_vector_type(16)));

// native v_exp_f32 (2^x) — NOT __exp2f (glibc macro collision on gfx950 build)
#define EXP2F(x) __builtin_amdgcn_exp2f(x)

// ===========================================================================
// Layouts:
//  xs  [row][icb][px][32]      bf16  — conv B-fragment native (r7-verified)
//  wtf [tap][ocb][icb][512]    bf16  — conv A-fragment native
//  xpk [b*8+h][y][x][4]        fp32  — conv_in K output, PRE-NORMALIZED k-hat
//  xpv [b*8+h][y][x][4]        fp32  — conv_in V output (raw)
//  fq4 [b*8+h][y][x][4]        fp32  — conv_f Q output, PRE-SCALED
//                                      q-hat * exp(min(ls,LOGMAX)) * LOG2E
//                                      (ls = lsc for b0/b1, lrlsc for b2)
//  v1      [h][y][x][4]        fp32  — axial_row output (only export now)
//  knT/qnT/v1T [h][x][y][4]    fp32  — transpose3 of (xpk b2, fq4 b2, v1)
// r10: axial 128thr x 2q -> 256thr x 1q: 52 -> 45.5 us, VALUBusy 62%.
// r11 post-mortem of r10: axial was LDS-return-BW bound: 2 broadcast
//      ds_read_b128/iter x 30 waves/CU x 240 iters x ~8cy = 48 us ~= measured.
//      Fix: k/v are wave-uniform -> load via s_load_dwordx16 into SGPRs
//      (scalar pipe, zero LDS), pre-normalize K / pre-scale Q in the conv
//      epilogues so axial consumes them directly and exports only v1.
// ===========================================================================

__global__ __launch_bounds__(256) void to_xs_pad(
    const float* __restrict__ in, __bf16* __restrict__ xs)
{
    const int p = blockIdx.x * 256 + threadIdx.x;
    if (p >= PW * PW) return;
    const int row = p / PW, px = p % PW;
    const bool border = (row == 0 || row == PW - 1 || px == 0 || px == PW - 1);
    union { __bf16 h[32]; uint4 u[4]; } pk;
#pragma unroll
    for (int icb = 0; icb < 3; ++icb) {
        uint4* op = (uint4*)(xs + (((size_t)row * 3 + icb) * PW + px) * 32);
        if (border) {
#pragma unroll
            for (int b = 0; b < 4; ++b) op[b] = make_uint4(0, 0, 0, 0);
        } else {
            const float* ip = in + (size_t)(icb * 32) * PP + (row - 1) * WW + (px - 1);
#pragma unroll
            for (int j = 0; j < 32; ++j) pk.h[j] = (__bf16)ip[(size_t)j * PP];
#pragma unroll
            for (int b = 0; b < 4; ++b) op[b] = pk.u[b];
        }
    }
}

__global__ __launch_bounds__(256) void wt_frag(
    const float* __restrict__ w, __bf16* __restrict__ wtf, int OC)
{
    const int t = blockIdx.x * 256 + threadIdx.x;
    if (t >= 9 * (OC / 16) * 3 * 64) return;
    const int lane = t & 63;
    const int rest = t >> 6;
    const int icb  = rest % 3;
    const int to   = rest / 3;
    const int ocb  = to % (OC / 16);
    const int tap  = to / (OC / 16);
    const int ln = lane & 15, quad = lane >> 4;
    const int oc  = ocb * 16 + ln;
    const int ic0 = icb * 32 + quad * 8;
    __bf16* op = wtf + (size_t)rest * 512 + lane * 8;
#pragma unroll
    for (int d = 0; d < 8; ++d)
        op[d] = (__bf16)w[(size_t)(oc * 96 + ic0 + d) * 9 + tap];
}

__global__ __launch_bounds__(256) void zero_border_xs(__bf16* __restrict__ ys)
{
    const int idx = blockIdx.x * 256 + threadIdx.x;
    if (idx >= 4 * PW) return;
    const int g = idx / PW, i = idx % PW;
    int row, px;
    if (g == 0)      { row = 0;      px = i; }
    else if (g == 1) { row = PW - 1; px = i; }
    else if (g == 2) { row = i;      px = 0; }
    else             { row = i;      px = PW - 1; }
#pragma unroll
    for (int icb = 0; icb < 3; ++icb) {
        uint4* op = (uint4*)(ys + (((size_t)row * 3 + icb) * PW + px) * 32);
#pragma unroll
        for (int b = 0; b < 4; ++b) op[b] = make_uint4(0, 0, 0, 0);
    }
}

// ---------------------------------------------------------------------------
// Implicit-GEMM 3x3 conv on MFMA (r7-verified core). EPI selects epilogue:
//  0: NCHW fp32 (conv_out)
//  1: xpk/xpv f32x4 (conv_in) — K side (out0) stored PRE-NORMALIZED
//  2: fq4 (conv_f) — stored PRE-SCALED: q-hat * scale_h * LOG2E
// Each f32x4 epilogue vector is a complete head (hd=4) vector, so the
// cosine normalization is local to the epilogue (r11).
// ---------------------------------------------------------------------------
template <int OC, int MT, int EPI>
__global__ __launch_bounds__(256) void conv3x3_mfma(
    const __bf16* __restrict__ xs, const __bf16* __restrict__ wtf,
    const float* __restrict__ bias, float* __restrict__ out0,
    float* __restrict__ out1, const float* __restrict__ lsc,
    const float* __restrict__ lrlsc)
{
    const int bid   = blockIdx.x;
    const int group = bid / 24;
    const int w24   = bid % 24;
    const int z     = w24 >> 3;
    const int xy    = group * 8 + (w24 & 7);
    if (xy >= 450) return;
    const int x0  = (xy % 15) * 16;
    const int y0  = (xy / 15) * 8;
    const int oc0 = z * (MT * 16);
    const int ocb0 = oc0 / 16;

    const int wave = threadIdx.x >> 6;
    const int lane = threadIdx.x & 63;
    const int ln   = lane & 15;
    const int quad = lane >> 4;
    const int r0   = y0 + wave * 2;

    f32x4 acc[MT][2] = {};
    bf16x8 a[2][MT], b[2][2];

    const __bf16* abase = wtf + (size_t)lane * 8;
    const __bf16* bbase = xs + (size_t)ln * 32 + quad * 8;

#define LOAD_CHUNK(c, buf)                                                    \
    {                                                                         \
        const int tap_ = (c) / 3, icb_ = (c) % 3;                             \
        const int dy_ = tap_ / 3, dx_ = tap_ % 3;                             \
        const __bf16* ap_ = abase + (size_t)((tap_ * (OC / 16) + ocb0) * 3 + icb_) * 512; \
        _Pragma("unroll")                                                     \
        for (int mi = 0; mi < MT; ++mi)                                       \
            a[buf][mi] = *(const bf16x8*)(ap_ + (size_t)mi * 1536);           \
        _Pragma("unroll")                                                     \
        for (int ni = 0; ni < 2; ++ni)                                        \
            b[buf][ni] = *(const bf16x8*)(bbase +                             \
                (((size_t)(r0 + ni + dy_) * 3 + icb_) * PW + x0 + dx_) * 32); \
    }

    LOAD_CHUNK(0, 0)
#pragma unroll
    for (int c = 0; c < 27; ++c) {
        const int cur = c & 1, nxt = cur ^ 1;
        if (c < 26) LOAD_CHUNK(c + 1, nxt)
#pragma unroll
        for (int mi = 0; mi < MT; ++mi)
#pragma unroll
            for (int ni = 0; ni < 2; ++ni)
                acc[mi][ni] = __builtin_amdgcn_mfma_f32_16x16x32_bf16(
                    a[cur][mi], b[cur][ni], acc[cur ? mi : mi][ni], 0, 0, 0);
    }
#undef LOAD_CHUNK

    if constexpr (EPI == 0) {
#pragma unroll
        for (int mi = 0; mi < MT; ++mi) {
#pragma unroll
            for (int r = 0; r < 4; ++r) {
                const int oc = oc0 + mi * 16 + quad * 4 + r;
                const float bv = bias[oc];
#pragma unroll
                for (int ni = 0; ni < 2; ++ni)
                    out0[(size_t)oc * PP + (r0 + ni) * WW + x0 + ln] = acc[mi][ni][r] + bv;
            }
        }
    } else if constexpr (EPI == 1) {
#pragma unroll
        for (int mi = 0; mi < MT; ++mi) {
            const f32x4 bv = *(const f32x4*)(bias + oc0 + mi * 16 + quad * 4);
            float* dst = (mi >> 1) ? out1 : out0;
            const int h8 = z * 8 + (mi & 1) * 4 + quad;
#pragma unroll
            for (int ni = 0; ni < 2; ++ni) {
                f32x4 o = acc[mi][ni] + bv;
                if ((mi >> 1) == 0) {  // K side: store k-hat
                    const float ksq = o[0]*o[0] + o[1]*o[1] + o[2]*o[2] + o[3]*o[3];
                    o *= 1.0f / fmaxf(sqrtf(ksq), 1e-12f);
                }
                *(f32x4*)(dst + (((size_t)h8 * 240 + r0 + ni) * 240 + x0 + ln) * 4) = o;
            }
        }
    } else {
#pragma unroll
        for (int mi = 0; mi < MT; ++mi) {
            const f32x4 bv = *(const f32x4*)(bias + oc0 + mi * 16 + quad * 4);
            const int h8 = z * 8 + mi * 4 + quad;
            const int br = h8 >> 3, hh = h8 & 7;
            const float ls = (br == 2) ? lrlsc[hh] : lsc[hh];
            const float qsc = __expf(fminf(ls, LOG_MAX_C)) * LOG2E;
#pragma unroll
            for (int ni = 0; ni < 2; ++ni) {
                f32x4 o = acc[mi][ni] + bv;
                const float qsq = o[0]*o[0] + o[1]*o[1] + o[2]*o[2] + o[3]*o[3];
                o *= qsc / fmaxf(sqrtf(qsq), 1e-12f);
                *(f32x4*)(out0 + (((size_t)h8 * 240 + r0 + ni) * 240 + x0 + ln) * 4) = o;
            }
        }
    }
}

// ---------------------------------------------------------------------------
// Window cosine attention, branches 0+1 FUSED in one launch (4608 blocks).
// br = bid/2304 selects branch (channel slice, shifts, icb); 2304%8==0 keeps
// the XCD swizzle property on the low bits. Fixed-max single-pass softmax.
// r11: inputs arrive pre-normalized (k-hat) / pre-scaled (q-hat*qs), so the
// per-element normalize is gone; negM2 = -scale*LOG2E as before.
// ---------------------------------------------------------------------------
__global__ __launch_bounds__(256) void win_attn_kernel(
    const float* __restrict__ fq4, const float* __restrict__ xpk,
    const float* __restrict__ xpv, const float* __restrict__ lsc,
    __bf16* __restrict__ ys)
{
    __shared__ f32x4 ks[8][25];
    __shared__ f32x4 vs[8][25];
    const int bid = blockIdx.x;
    const int br  = bid / 2304;          // 0: plain, 1: shifted
    const int id  = bid % 2304;
    const int wi  = id / 288;
    const int g   = id % 288;
    const int wy  = g / 6;
    const int wx  = (g % 6) * 8 + wi;
    const int gshift = br * 3, sshift = br * 2;
    const size_t choff = (size_t)br * 32 * PP;
    const int t = threadIdx.x;
    const int h = t / 25, i = t % 25;
    f32x4 qn = {0, 0, 0, 0};
    float negM2 = 0.f;
    int oy = 0, ox = 0;

    if (t < 200) {
        const int y = (wy * 5 + i / 5 + gshift) % HH;
        const int x = (wx * 5 + i % 5 + gshift) % WW;
        const size_t p4 = choff + (((size_t)h * 240 + y) * 240 + x) * 4;
        qn = *(const f32x4*)(fq4 + p4);              // pre-scaled q
        ks[h][i] = *(const f32x4*)(xpk + p4);        // pre-normalized k
        vs[h][i] = *(const f32x4*)(xpv + p4);
        const float scale = __expf(fminf(lsc[h], LOG_MAX_C));
        negM2 = -scale * LOG2E;
        oy = (wy * 5 + i / 5 + sshift) % HH;
        ox = (wx * 5 + i % 5 + sshift) % WW;
    }
    __syncthreads();
    if (t < 200) {
        float l = 0.f;
        f32x4 acc = {0, 0, 0, 0};
#pragma unroll
        for (int j = 0; j < 25; ++j) {
            const f32x4 kk = ks[h][j];
            const float s = fmaf(qn[0], kk[0],
                            fmaf(qn[1], kk[1],
                            fmaf(qn[2], kk[2],
                            fmaf(qn[3], kk[3], negM2))));
            const float p = EXP2F(s);
            l += p;
            acc += vs[h][j] * p;
        }
        const float linv = 1.0f / l;
        union { __bf16 h4[4]; uint2 u; } o;
#pragma unroll
        for (int d = 0; d < 4; ++d) o.h4[d] = (__bf16)(acc[d] * linv);
        *(uint2*)(ys + (((size_t)(oy + 1) * 3 + br) * PW + ox + 1) * 32 + h * 4) = o.u;
    }
}

// ---------------------------------------------------------------------------
// Axial row attention (over w). Block (y,h), 256 threads, 1 query/thread.
// r11: k/v are wave-uniform per j -> s_load_dwordx16 into SGPRs (scalar
// pipe), zero LDS. Inputs pre-normalized/pre-scaled by conv epilogues.
// Only export is v1 (kn/qn now read straight from xpk/fq4 b2 by transpose3).
// All 256 threads run the uniform j-loop (no divergent CF around s_load);
// lanes 240..255 compute a clamped query and skip the store.
// ---------------------------------------------------------------------------
__global__ __launch_bounds__(256) void axial_row_kernel(
    const float* __restrict__ fq4b, const float* __restrict__ xpkb,
    const float* __restrict__ xpvb, const float* __restrict__ lsc,
    float* __restrict__ v1)
{
    const int t = threadIdx.x;
    const int y = blockIdx.x, h = blockIdx.y;

    const float scale = __expf(fminf(lsc[h], LOG_MAX_C));
    const float negM2 = -scale * LOG2E;
    const int tq = t < 239 ? t : 239;
    const size_t rowb = ((size_t)h * 240 + y) * 240;
    const f32x4 qreg = *(const f32x4*)(fq4b + (rowb + tq) * 4);
    const float* kp0 = xpkb + rowb * 4;
    const float* vp0 = xpvb + rowb * 4;

    float l = 0.f;
    f32x4 a = {0, 0, 0, 0};
    for (int c = 0; c < 60; ++c) {       // 4 keys per chunk
        f32x16 kc, vc;
        asm volatile(
            "s_load_dwordx16 %0, %2, 0x0\n\t"
            "s_load_dwordx16 %1, %3, 0x0\n\t"
            "s_waitcnt lgkmcnt(0)"
            : "=&s"(kc), "=&s"(vc)
            : "s"(kp0 + c * 16), "s"(vp0 + c * 16));
#pragma unroll
        for (int jj = 0; jj < 4; ++jj) {
            const float s = fmaf(qreg[0], kc[jj * 4 + 0],
                            fmaf(qreg[1], kc[jj * 4 + 1],
                            fmaf(qreg[2], kc[jj * 4 + 2],
                            fmaf(qreg[3], kc[jj * 4 + 3], negM2))));
            const float p = EXP2F(s);
            l += p;
            a[0] = fmaf(vc[jj * 4 + 0], p, a[0]);
            a[1] = fmaf(vc[jj * 4 + 1], p, a[1]);
            a[2] = fmaf(vc[jj * 4 + 2], p, a[2]);
            a[3] = fmaf(vc[jj * 4 + 3], p, a[3]);
        }
    }
    if (t < 240) {
        const float li = 1.0f / l;
        *(f32x4*)(v1 + (rowb + t) * 4) = a * li;
    }
}

// ---------------------------------------------------------------------------
// LDS-tiled (y,x)-transpose of 3 tensors [8][240][240][4] f32 -> [8][240][240][4].
// 16x16 f32x4 tiles, 17-padded rows (2-way LDS aliasing only = free, m136).
// Reads and writes both coalesced; all writers of a 64B line in one block.
// r11 sources: (xpk b2 = k-hat, fq4 b2 = q-hat*qs, v1).
// ---------------------------------------------------------------------------
__global__ __launch_bounds__(256) void transpose3(
    const float* __restrict__ a0, const float* __restrict__ a1,
    const float* __restrict__ a2, float* __restrict__ t0,
    float* __restrict__ t1, float* __restrict__ t2)
{
    __shared__ f32x4 tile[16][17];
    const int t = threadIdx.x, ty = t >> 4, tx = t & 15;
    const int h = blockIdx.z, y0 = blockIdx.y * 16, x0 = blockIdx.x * 16;
    const size_t rd = (((size_t)h * 240 + y0 + ty) * 240 + x0 + tx) * 4;
    const size_t wr = (((size_t)h * 240 + x0 + ty) * 240 + y0 + tx) * 4;
    const float* srcs[3] = {a0, a1, a2};
    float* dsts[3] = {t0, t1, t2};
#pragma unroll
    for (int n = 0; n < 3; ++n) {
        tile[ty][tx] = *(const f32x4*)(srcs[n] + rd);
        __syncthreads();
        *(f32x4*)(dsts[n] + wr) = tile[tx][ty];
        __syncthreads();
    }
}

// ---------------------------------------------------------------------------
// Axial column attention (over h). Same r11 scalar-pipe structure as row.
// ---------------------------------------------------------------------------
__global__ __launch_bounds__(256) void axial_col_kernel(
    const float* __restrict__ knT, const float* __restrict__ qnT,
    const float* __restrict__ v1T, const float* __restrict__ lsc,
    __bf16* __restrict__ ys)
{
    const int bid = blockIdx.x;
    const int wi  = bid / 120;
    const int g   = bid % 120;
    const int h   = g % 8;
    const int x   = (g / 8) * 16 + wi;
    const int t = threadIdx.x;

    const float scale = __expf(fminf(lsc[h], LOG_MAX_C));
    const float negM2 = -scale * LOG2E;
    const int ty = t < 239 ? t : 239;
    const size_t rowb = ((size_t)h * 240 + x) * 240;
    const f32x4 qreg = *(const f32x4*)(qnT + (rowb + ty) * 4);
    const float* kp0 = knT + rowb * 4;
    const float* vp0 = v1T + rowb * 4;

    float l = 0.f;
    f32x4 a = {0, 0, 0, 0};
    for (int c = 0; c < 60; ++c) {
        f32x16 kc, vc;
        asm volatile(
            "s_load_dwordx16 %0, %2, 0x0\n\t"
            "s_load_dwordx16 %1, %3, 0x0\n\t"
            "s_waitcnt lgkmcnt(0)"
            : "=&s"(kc), "=&s"(vc)
            : "s"(kp0 + c * 16), "s"(vp0 + c * 16));
#pragma unroll
        for (int jj = 0; jj < 4; ++jj) {
            const float s = fmaf(qreg[0], kc[jj * 4 + 0],
                            fmaf(qreg[1], kc[jj * 4 + 1],
                            fmaf(qreg[2], kc[jj * 4 + 2],
                            fmaf(qreg[3], kc[jj * 4 + 3], negM2))));
            const float p = EXP2F(s);
            l += p;
            a[0] = fmaf(vc[jj * 4 + 0], p, a[0]);
            a[1] = fmaf(vc[jj * 4 + 1], p, a[1]);
            a[2] = fmaf(vc[jj * 4 + 2], p, a[2]);
            a[3] = fmaf(vc[jj * 4 + 3], p, a[3]);
        }
    }
    if (t < 240) {
        const float li = 1.0f / l;
        const f32x4 o4 = a * li;
        union { __bf16 h4[4]; uint2 u; } o;
#pragma unroll
        for (int d = 0; d < 4; ++d) o.h4[d] = (__bf16)o4[d];
        *(uint2*)(ys + (((size_t)(t + 1) * 3 + 2) * PW + x + 1) * 32 + h * 4) = o.u;
    }
}

// ---------------------------------------------------------------------------
// Pipeline. Workspace (fp32 units):
//   xpk 96PP | xpv 96PP | fq4 96PP | xs/ys bf16 | wtf_in | wtf_f | wtf_o
// Aliases (b0/b1 slices of xpk/xpv/fq4 are dead after fused win_attn):
//   v1  = xpv b0 | knT = xpv b1 | qnT = fq4 b0 | v1T = fq4 b1
// axial_row reads only b2 slices, writes v1; transpose3 reads
// (xpk b2, fq4 b2, v1), writes *T; axial_col reads *T.
// Stream order guarantees safety.
// ---------------------------------------------------------------------------
extern "C" void kernel_launch(void* const* d_in, const int* in_sizes, int n_in,
                              void* d_out, int out_size, void* d_ws, size_t ws_size,
                              hipStream_t stream)
{
    const float* x     = (const float*)d_in[0];
    const float* w_in  = (const float*)d_in[1];
    const float* b_in  = (const float*)d_in[2];
    const float* w_f   = (const float*)d_in[3];
    const float* b_f   = (const float*)d_in[4];
    const float* w_out = (const float*)d_in[5];
    const float* b_out = (const float*)d_in[6];
    const float* lsc   = (const float*)d_in[7];
    const float* lrlsc = (const float*)d_in[8];
    float* out = (float*)d_out;

    float* ws  = (float*)d_ws;
    float* xpk = ws;                   // 96*PP
    float* xpv = xpk + 96 * PP;        // 96*PP
    float* fq4 = xpv + 96 * PP;        // 96*PP
    __bf16* xs     = (__bf16*)(fq4 + 96 * PP);            // 242*3*242*32 bf16
    __bf16* wtf_in = xs + (size_t)PW * 3 * PW * 32;
    __bf16* wtf_f  = wtf_in + 9 * 12 * 3 * 512;
    __bf16* wtf_o  = wtf_f + 9 * 6 * 3 * 512;
    __bf16* ys     = xs;               // alias: xs dead after conv_in/conv_f

    float* v1  = xpv;                  // b0, dead after fused win_attn
    float* knT = xpv + 32 * PP;        // b1
    float* qnT = fq4;                  // b0
    float* v1T = fq4 + 32 * PP;        // b1

    wt_frag<<<(9 * 12 * 3 * 64 + 255) / 256, 256, 0, stream>>>(w_in, wtf_in, 192);
    wt_frag<<<(9 * 6 * 3 * 64 + 255) / 256, 256, 0, stream>>>(w_f, wtf_f, 96);
    wt_frag<<<(9 * 6 * 3 * 64 + 255) / 256, 256, 0, stream>>>(w_out, wtf_o, 96);
    to_xs_pad<<<(PW * PW + 255) / 256, 256, 0, stream>>>(x, xs);

    conv3x3_mfma<192, 4, 1><<<1368, 256, 0, stream>>>(xs, wtf_in, b_in, xpk, xpv,
                                                      nullptr, nullptr);
    conv3x3_mfma<96, 2, 2><<<1368, 256, 0, stream>>>(xs, wtf_f, b_f, fq4, nullptr,
                                                     lsc, lrlsc);

    zero_border_xs<<<(4 * PW + 255) / 256, 256, 0, stream>>>(ys);

    // fused window attention (branches 0 + 1)
    win_attn_kernel<<<4608, 256, 0, stream>>>(fq4, xpk, xpv, lsc, ys);

    axial_row_kernel<<<dim3(240, 8), 256, 0, stream>>>(
        fq4 + 64 * PP, xpk + 64 * PP, xpv + 64 * PP, lrlsc, v1);
    transpose3<<<dim3(15, 15, 8), 256, 0, stream>>>(
        xpk + 64 * PP, fq4 + 64 * PP, v1, knT, qnT, v1T);
    axial_col_kernel<<<1920, 256, 0, stream>>>(knT, qnT, v1T, lrlsc, ys);

    conv3x3_mfma<96, 2, 0><<<1368, 256, 0, stream>>>(ys, wtf_o, b_out, out, nullptr,
                                                     nullptr, nullptr);
}

// Round 3
// 301.663 us; speedup vs baseline: 1.0552x; 1.0552x over previous
//
#include <hip/hip_runtime.h>
#include <math.h>

#define HH 240
#define WW 240
#define PP (HH * WW)
#define PW 242              // padded height/width for conv input
#define LOG_MAX_C 4.605170185988091f  // log(100)
#define LOG2E 1.442695040888963f

typedef __bf16 bf16x8 __attribute__((ext_vector_type(8)));
typedef float  f32x4  __attribute__((ext_vector_type(4)));

// native v_exp_f32 (2^x) — NOT __exp2f (glibc macro collision on gfx950 build)
#define EXP2F(x) __builtin_amdgcn_exp2f(x)

// ===========================================================================
// Layouts:
//  xs  [row][icb][px][32]      bf16  — conv B-fragment native (r7-verified)
//  wtf [tap][ocb][icb][512]    bf16  — conv A-fragment native
//  xpk [b*8+h][y][x][4]        fp32  — conv_in K output, PRE-NORMALIZED k-hat
//  xpv [b*8+h][y][x][4]        fp32  — conv_in V output (raw)
//  fq4 [b*8+h][y][x][4]        fp32  — conv_f Q output, PRE-SCALED
//                                      q-hat * exp(min(ls,LOGMAX)) * LOG2E
//  v1      [h][y][x][4]        fp32  — axial_row output (only export)
//  knT/qnT/v1T [h][x][y][4]    fp32  — transpose3 of (xpk b2, fq4 b2, v1)
// History:
//  r10: axial 128x2q -> 256x1q: 52 -> 45.5 us (occupancy 22->44%).
//  r11: s_load scalar-pipe k/v FAILED (318 us): in-loop lgkmcnt(0) serializes
//       on ~200cy scalar latency; no pipelining through asm volatile.
//       KEPT from r11: conv-epilogue pre-normalize K / pre-scale Q.
//  r12: LDS broadcast again, but 2 ROWS/block + 2 QUERIES/thread (256 thr):
//       one ks/vs broadcast pair now feeds 36 VALU-cy (was 18) -> VALU-bound;
//       same wave count as r10-256x1q so occupancy holds.
// ===========================================================================

__global__ __launch_bounds__(256) void to_xs_pad(
    const float* __restrict__ in, __bf16* __restrict__ xs)
{
    const int p = blockIdx.x * 256 + threadIdx.x;
    if (p >= PW * PW) return;
    const int row = p / PW, px = p % PW;
    const bool border = (row == 0 || row == PW - 1 || px == 0 || px == PW - 1);
    union { __bf16 h[32]; uint4 u[4]; } pk;
#pragma unroll
    for (int icb = 0; icb < 3; ++icb) {
        uint4* op = (uint4*)(xs + (((size_t)row * 3 + icb) * PW + px) * 32);
        if (border) {
#pragma unroll
            for (int b = 0; b < 4; ++b) op[b] = make_uint4(0, 0, 0, 0);
        } else {
            const float* ip = in + (size_t)(icb * 32) * PP + (row - 1) * WW + (px - 1);
#pragma unroll
            for (int j = 0; j < 32; ++j) pk.h[j] = (__bf16)ip[(size_t)j * PP];
#pragma unroll
            for (int b = 0; b < 4; ++b) op[b] = pk.u[b];
        }
    }
}

__global__ __launch_bounds__(256) void wt_frag(
    const float* __restrict__ w, __bf16* __restrict__ wtf, int OC)
{
    const int t = blockIdx.x * 256 + threadIdx.x;
    if (t >= 9 * (OC / 16) * 3 * 64) return;
    const int lane = t & 63;
    const int rest = t >> 6;
    const int icb  = rest % 3;
    const int to   = rest / 3;
    const int ocb  = to % (OC / 16);
    const int tap  = to / (OC / 16);
    const int ln = lane & 15, quad = lane >> 4;
    const int oc  = ocb * 16 + ln;
    const int ic0 = icb * 32 + quad * 8;
    __bf16* op = wtf + (size_t)rest * 512 + lane * 8;
#pragma unroll
    for (int d = 0; d < 8; ++d)
        op[d] = (__bf16)w[(size_t)(oc * 96 + ic0 + d) * 9 + tap];
}

__global__ __launch_bounds__(256) void zero_border_xs(__bf16* __restrict__ ys)
{
    const int idx = blockIdx.x * 256 + threadIdx.x;
    if (idx >= 4 * PW) return;
    const int g = idx / PW, i = idx % PW;
    int row, px;
    if (g == 0)      { row = 0;      px = i; }
    else if (g == 1) { row = PW - 1; px = i; }
    else if (g == 2) { row = i;      px = 0; }
    else             { row = i;      px = PW - 1; }
#pragma unroll
    for (int icb = 0; icb < 3; ++icb) {
        uint4* op = (uint4*)(ys + (((size_t)row * 3 + icb) * PW + px) * 32);
#pragma unroll
        for (int b = 0; b < 4; ++b) op[b] = make_uint4(0, 0, 0, 0);
    }
}

// ---------------------------------------------------------------------------
// Implicit-GEMM 3x3 conv on MFMA (r7-verified core). EPI selects epilogue:
//  0: NCHW fp32 (conv_out)
//  1: xpk/xpv f32x4 (conv_in) — K side (out0) stored PRE-NORMALIZED
//  2: fq4 (conv_f) — stored PRE-SCALED: q-hat * scale_h * LOG2E
// Each f32x4 epilogue vector is a complete head (hd=4) vector, so the
// cosine normalization is local to the epilogue (r11).
// ---------------------------------------------------------------------------
template <int OC, int MT, int EPI>
__global__ __launch_bounds__(256) void conv3x3_mfma(
    const __bf16* __restrict__ xs, const __bf16* __restrict__ wtf,
    const float* __restrict__ bias, float* __restrict__ out0,
    float* __restrict__ out1, const float* __restrict__ lsc,
    const float* __restrict__ lrlsc)
{
    const int bid   = blockIdx.x;
    const int group = bid / 24;
    const int w24   = bid % 24;
    const int z     = w24 >> 3;
    const int xy    = group * 8 + (w24 & 7);
    if (xy >= 450) return;
    const int x0  = (xy % 15) * 16;
    const int y0  = (xy / 15) * 8;
    const int oc0 = z * (MT * 16);
    const int ocb0 = oc0 / 16;

    const int wave = threadIdx.x >> 6;
    const int lane = threadIdx.x & 63;
    const int ln   = lane & 15;
    const int quad = lane >> 4;
    const int r0   = y0 + wave * 2;

    f32x4 acc[MT][2] = {};
    bf16x8 a[2][MT], b[2][2];

    const __bf16* abase = wtf + (size_t)lane * 8;
    const __bf16* bbase = xs + (size_t)ln * 32 + quad * 8;

#define LOAD_CHUNK(c, buf)                                                    \
    {                                                                         \
        const int tap_ = (c) / 3, icb_ = (c) % 3;                             \
        const int dy_ = tap_ / 3, dx_ = tap_ % 3;                             \
        const __bf16* ap_ = abase + (size_t)((tap_ * (OC / 16) + ocb0) * 3 + icb_) * 512; \
        _Pragma("unroll")                                                     \
        for (int mi = 0; mi < MT; ++mi)                                       \
            a[buf][mi] = *(const bf16x8*)(ap_ + (size_t)mi * 1536);           \
        _Pragma("unroll")                                                     \
        for (int ni = 0; ni < 2; ++ni)                                        \
            b[buf][ni] = *(const bf16x8*)(bbase +                             \
                (((size_t)(r0 + ni + dy_) * 3 + icb_) * PW + x0 + dx_) * 32); \
    }

    LOAD_CHUNK(0, 0)
#pragma unroll
    for (int c = 0; c < 27; ++c) {
        const int cur = c & 1, nxt = cur ^ 1;
        if (c < 26) LOAD_CHUNK(c + 1, nxt)
#pragma unroll
        for (int mi = 0; mi < MT; ++mi)
#pragma unroll
            for (int ni = 0; ni < 2; ++ni)
                acc[mi][ni] = __builtin_amdgcn_mfma_f32_16x16x32_bf16(
                    a[cur][mi], b[cur][ni], acc[mi][ni], 0, 0, 0);
    }
#undef LOAD_CHUNK

    if constexpr (EPI == 0) {
#pragma unroll
        for (int mi = 0; mi < MT; ++mi) {
#pragma unroll
            for (int r = 0; r < 4; ++r) {
                const int oc = oc0 + mi * 16 + quad * 4 + r;
                const float bv = bias[oc];
#pragma unroll
                for (int ni = 0; ni < 2; ++ni)
                    out0[(size_t)oc * PP + (r0 + ni) * WW + x0 + ln] = acc[mi][ni][r] + bv;
            }
        }
    } else if constexpr (EPI == 1) {
#pragma unroll
        for (int mi = 0; mi < MT; ++mi) {
            const f32x4 bv = *(const f32x4*)(bias + oc0 + mi * 16 + quad * 4);
            float* dst = (mi >> 1) ? out1 : out0;
            const int h8 = z * 8 + (mi & 1) * 4 + quad;
#pragma unroll
            for (int ni = 0; ni < 2; ++ni) {
                f32x4 o = acc[mi][ni] + bv;
                if ((mi >> 1) == 0) {  // K side: store k-hat
                    const float ksq = o[0]*o[0] + o[1]*o[1] + o[2]*o[2] + o[3]*o[3];
                    o *= 1.0f / fmaxf(sqrtf(ksq), 1e-12f);
                }
                *(f32x4*)(dst + (((size_t)h8 * 240 + r0 + ni) * 240 + x0 + ln) * 4) = o;
            }
        }
    } else {
#pragma unroll
        for (int mi = 0; mi < MT; ++mi) {
            const f32x4 bv = *(const f32x4*)(bias + oc0 + mi * 16 + quad * 4);
            const int h8 = z * 8 + mi * 4 + quad;
            const int br = h8 >> 3, hh = h8 & 7;
            const float ls = (br == 2) ? lrlsc[hh] : lsc[hh];
            const float qsc = __expf(fminf(ls, LOG_MAX_C)) * LOG2E;
#pragma unroll
            for (int ni = 0; ni < 2; ++ni) {
                f32x4 o = acc[mi][ni] + bv;
                const float qsq = o[0]*o[0] + o[1]*o[1] + o[2]*o[2] + o[3]*o[3];
                o *= qsc / fmaxf(sqrtf(qsq), 1e-12f);
                *(f32x4*)(out0 + (((size_t)h8 * 240 + r0 + ni) * 240 + x0 + ln) * 4) = o;
            }
        }
    }
}

// ---------------------------------------------------------------------------
// Window cosine attention, branches 0+1 FUSED in one launch (4608 blocks).
// br = bid/2304 selects branch (channel slice, shifts, icb); 2304%8==0 keeps
// the XCD swizzle property on the low bits. Fixed-max single-pass softmax.
// r11: inputs arrive pre-normalized (k-hat) / pre-scaled (q-hat*qs).
// ---------------------------------------------------------------------------
__global__ __launch_bounds__(256) void win_attn_kernel(
    const float* __restrict__ fq4, const float* __restrict__ xpk,
    const float* __restrict__ xpv, const float* __restrict__ lsc,
    __bf16* __restrict__ ys)
{
    __shared__ f32x4 ks[8][25];
    __shared__ f32x4 vs[8][25];
    const int bid = blockIdx.x;
    const int br  = bid / 2304;          // 0: plain, 1: shifted
    const int id  = bid % 2304;
    const int wi  = id / 288;
    const int g   = id % 288;
    const int wy  = g / 6;
    const int wx  = (g % 6) * 8 + wi;
    const int gshift = br * 3, sshift = br * 2;
    const size_t choff = (size_t)br * 32 * PP;
    const int t = threadIdx.x;
    const int h = t / 25, i = t % 25;
    f32x4 qn = {0, 0, 0, 0};
    float negM2 = 0.f;
    int oy = 0, ox = 0;

    if (t < 200) {
        const int y = (wy * 5 + i / 5 + gshift) % HH;
        const int x = (wx * 5 + i % 5 + gshift) % WW;
        const size_t p4 = choff + (((size_t)h * 240 + y) * 240 + x) * 4;
        qn = *(const f32x4*)(fq4 + p4);              // pre-scaled q
        ks[h][i] = *(const f32x4*)(xpk + p4);        // pre-normalized k
        vs[h][i] = *(const f32x4*)(xpv + p4);
        const float scale = __expf(fminf(lsc[h], LOG_MAX_C));
        negM2 = -scale * LOG2E;
        oy = (wy * 5 + i / 5 + sshift) % HH;
        ox = (wx * 5 + i % 5 + sshift) % WW;
    }
    __syncthreads();
    if (t < 200) {
        float l = 0.f;
        f32x4 acc = {0, 0, 0, 0};
#pragma unroll
        for (int j = 0; j < 25; ++j) {
            const f32x4 kk = ks[h][j];
            const float s = fmaf(qn[0], kk[0],
                            fmaf(qn[1], kk[1],
                            fmaf(qn[2], kk[2],
                            fmaf(qn[3], kk[3], negM2))));
            const float p = EXP2F(s);
            l += p;
            acc += vs[h][j] * p;
        }
        const float linv = 1.0f / l;
        union { __bf16 h4[4]; uint2 u; } o;
#pragma unroll
        for (int d = 0; d < 4; ++d) o.h4[d] = (__bf16)(acc[d] * linv);
        *(uint2*)(ys + (((size_t)(oy + 1) * 3 + br) * PW + ox + 1) * 32 + h * 4) = o.u;
    }
}

// ---------------------------------------------------------------------------
// Axial row attention (over w). r12: 2 rows/block, 2 queries/thread, 256thr.
// Waves 0,1 -> row y0; waves 2,3 -> row y0+1 (half = t>>7, wave-aligned so
// ks[half][j] broadcasts stay wave-uniform). Each ks/vs broadcast pair feeds
// 36 VALU-cycles (18 instrs x 2cy) -> VALU-bound, not LDS-return-bound.
// Inputs pre-normalized/pre-scaled by conv epilogues; only export is v1.
// ---------------------------------------------------------------------------
__global__ __launch_bounds__(256) void axial_row_kernel(
    const float* __restrict__ fq4b, const float* __restrict__ xpkb,
    const float* __restrict__ xpvb, const float* __restrict__ lsc,
    float* __restrict__ v1)
{
    __shared__ f32x4 ks[2][240];
    __shared__ f32x4 vs[2][240];
    const int t = threadIdx.x;
    const int half = t >> 7, tl = t & 127;
    const int y = blockIdx.x * 2 + half, h = blockIdx.y;

    const float scale = __expf(fminf(lsc[h], LOG_MAX_C));
    const float negM2 = -scale * LOG2E;
    const size_t rowb = ((size_t)h * 240 + y) * 240;
    f32x4 qreg[2] = {};

    if (tl < 120) {
#pragma unroll
        for (int s = 0; s < 2; ++s) {
            const int i = tl + s * 120;
            const size_t p4 = (rowb + i) * 4;
            ks[half][i] = *(const f32x4*)(xpkb + p4);
            vs[half][i] = *(const f32x4*)(xpvb + p4);
            qreg[s] = *(const f32x4*)(fq4b + p4);
        }
    }
    __syncthreads();
    if (tl < 120) {
        float l0 = 0.f, l1 = 0.f;
        f32x4 a0 = {0, 0, 0, 0}, a1 = {0, 0, 0, 0};
#pragma unroll 4
        for (int j = 0; j < 240; ++j) {
            const f32x4 kk = ks[half][j];
            const f32x4 vv = vs[half][j];
            const float s0 = fmaf(qreg[0][0], kk[0],
                             fmaf(qreg[0][1], kk[1],
                             fmaf(qreg[0][2], kk[2],
                             fmaf(qreg[0][3], kk[3], negM2))));
            const float s1 = fmaf(qreg[1][0], kk[0],
                             fmaf(qreg[1][1], kk[1],
                             fmaf(qreg[1][2], kk[2],
                             fmaf(qreg[1][3], kk[3], negM2))));
            const float p0 = EXP2F(s0);
            const float p1 = EXP2F(s1);
            l0 += p0; l1 += p1;
            a0 += vv * p0;
            a1 += vv * p1;
        }
        *(f32x4*)(v1 + (rowb + tl) * 4) = a0 * (1.0f / l0);
        *(f32x4*)(v1 + (rowb + tl + 120) * 4) = a1 * (1.0f / l1);
    }
}

// ---------------------------------------------------------------------------
// LDS-tiled (y,x)-transpose of 3 tensors [8][240][240][4] f32.
// 16x16 f32x4 tiles, 17-padded rows (2-way LDS aliasing only = free, m136).
// Sources: (xpk b2 = k-hat, fq4 b2 = q-hat*qs, v1).
// ---------------------------------------------------------------------------
__global__ __launch_bounds__(256) void transpose3(
    const float* __restrict__ a0, const float* __restrict__ a1,
    const float* __restrict__ a2, float* __restrict__ t0,
    float* __restrict__ t1, float* __restrict__ t2)
{
    __shared__ f32x4 tile[16][17];
    const int t = threadIdx.x, ty = t >> 4, tx = t & 15;
    const int h = blockIdx.z, y0 = blockIdx.y * 16, x0 = blockIdx.x * 16;
    const size_t rd = (((size_t)h * 240 + y0 + ty) * 240 + x0 + tx) * 4;
    const size_t wr = (((size_t)h * 240 + x0 + ty) * 240 + y0 + tx) * 4;
    const float* srcs[3] = {a0, a1, a2};
    float* dsts[3] = {t0, t1, t2};
#pragma unroll
    for (int n = 0; n < 3; ++n) {
        tile[ty][tx] = *(const f32x4*)(srcs[n] + rd);
        __syncthreads();
        *(f32x4*)(dsts[n] + wr) = tile[tx][ty];
        __syncthreads();
    }
}

// ---------------------------------------------------------------------------
// Axial column attention (over h). r12: same 2-cols/block, 2q/thread
// structure as axial_row, reading the transposed exports (contiguous in j).
// ---------------------------------------------------------------------------
__global__ __launch_bounds__(256) void axial_col_kernel(
    const float* __restrict__ knT, const float* __restrict__ qnT,
    const float* __restrict__ v1T, const float* __restrict__ lsc,
    __bf16* __restrict__ ys)
{
    __shared__ f32x4 ks[2][240];
    __shared__ f32x4 vs[2][240];
    const int bid = blockIdx.x;
    const int wi  = bid / 120;           // 0..7
    const int g   = bid % 120;
    const int h   = g % 8;
    const int xc  = g / 8;               // 0..14
    const int t = threadIdx.x;
    const int half = t >> 7, tl = t & 127;
    const int x = xc * 16 + wi * 2 + half;

    const float scale = __expf(fminf(lsc[h], LOG_MAX_C));
    const float negM2 = -scale * LOG2E;
    const size_t rowb = ((size_t)h * 240 + x) * 240;
    f32x4 qreg[2] = {};

    if (tl < 120) {
#pragma unroll
        for (int s = 0; s < 2; ++s) {
            const int i = tl + s * 120;
            const size_t pT = (rowb + i) * 4;
            ks[half][i] = *(const f32x4*)(knT + pT);
            vs[half][i] = *(const f32x4*)(v1T + pT);
            qreg[s] = *(const f32x4*)(qnT + pT);
        }
    }
    __syncthreads();
    if (tl < 120) {
        float l0 = 0.f, l1 = 0.f;
        f32x4 a0 = {0, 0, 0, 0}, a1 = {0, 0, 0, 0};
#pragma unroll 4
        for (int j = 0; j < 240; ++j) {
            const f32x4 kk = ks[half][j];
            const f32x4 vv = vs[half][j];
            const float s0 = fmaf(qreg[0][0], kk[0],
                             fmaf(qreg[0][1], kk[1],
                             fmaf(qreg[0][2], kk[2],
                             fmaf(qreg[0][3], kk[3], negM2))));
            const float s1 = fmaf(qreg[1][0], kk[0],
                             fmaf(qreg[1][1], kk[1],
                             fmaf(qreg[1][2], kk[2],
                             fmaf(qreg[1][3], kk[3], negM2))));
            const float p0 = EXP2F(s0);
            const float p1 = EXP2F(s1);
            l0 += p0; l1 += p1;
            a0 += vv * p0;
            a1 += vv * p1;
        }
#pragma unroll
        for (int s = 0; s < 2; ++s) {
            const f32x4 o4 = s ? a1 * (1.0f / l1) : a0 * (1.0f / l0);
            const int i = tl + s * 120;
            union { __bf16 h4[4]; uint2 u; } o;
#pragma unroll
            for (int d = 0; d < 4; ++d) o.h4[d] = (__bf16)o4[d];
            *(uint2*)(ys + (((size_t)(i + 1) * 3 + 2) * PW + x + 1) * 32 + h * 4) = o.u;
        }
    }
}

// ---------------------------------------------------------------------------
// Pipeline. Workspace (fp32 units):
//   xpk 96PP | xpv 96PP | fq4 96PP | xs/ys bf16 | wtf_in | wtf_f | wtf_o
// Aliases (b0/b1 slices of xpk/xpv/fq4 are dead after fused win_attn):
//   v1  = xpv b0 | knT = xpv b1 | qnT = fq4 b0 | v1T = fq4 b1
// axial_row reads only b2 slices, writes v1; transpose3 reads
// (xpk b2, fq4 b2, v1), writes *T; axial_col reads *T.
// Stream order guarantees safety.
// ---------------------------------------------------------------------------
extern "C" void kernel_launch(void* const* d_in, const int* in_sizes, int n_in,
                              void* d_out, int out_size, void* d_ws, size_t ws_size,
                              hipStream_t stream)
{
    const float* x     = (const float*)d_in[0];
    const float* w_in  = (const float*)d_in[1];
    const float* b_in  = (const float*)d_in[2];
    const float* w_f   = (const float*)d_in[3];
    const float* b_f   = (const float*)d_in[4];
    const float* w_out = (const float*)d_in[5];
    const float* b_out = (const float*)d_in[6];
    const float* lsc   = (const float*)d_in[7];
    const float* lrlsc = (const float*)d_in[8];
    float* out = (float*)d_out;

    float* ws  = (float*)d_ws;
    float* xpk = ws;                   // 96*PP
    float* xpv = xpk + 96 * PP;        // 96*PP
    float* fq4 = xpv + 96 * PP;        // 96*PP
    __bf16* xs     = (__bf16*)(fq4 + 96 * PP);            // 242*3*242*32 bf16
    __bf16* wtf_in = xs + (size_t)PW * 3 * PW * 32;
    __bf16* wtf_f  = wtf_in + 9 * 12 * 3 * 512;
    __bf16* wtf_o  = wtf_f + 9 * 6 * 3 * 512;
    __bf16* ys     = xs;               // alias: xs dead after conv_in/conv_f

    float* v1  = xpv;                  // b0, dead after fused win_attn
    float* knT = xpv + 32 * PP;        // b1
    float* qnT = fq4;                  // b0
    float* v1T = fq4 + 32 * PP;        // b1

    wt_frag<<<(9 * 12 * 3 * 64 + 255) / 256, 256, 0, stream>>>(w_in, wtf_in, 192);
    wt_frag<<<(9 * 6 * 3 * 64 + 255) / 256, 256, 0, stream>>>(w_f, wtf_f, 96);
    wt_frag<<<(9 * 6 * 3 * 64 + 255) / 256, 256, 0, stream>>>(w_out, wtf_o, 96);
    to_xs_pad<<<(PW * PW + 255) / 256, 256, 0, stream>>>(x, xs);

    conv3x3_mfma<192, 4, 1><<<1368, 256, 0, stream>>>(xs, wtf_in, b_in, xpk, xpv,
                                                      nullptr, nullptr);
    conv3x3_mfma<96, 2, 2><<<1368, 256, 0, stream>>>(xs, wtf_f, b_f, fq4, nullptr,
                                                     lsc, lrlsc);

    zero_border_xs<<<(4 * PW + 255) / 256, 256, 0, stream>>>(ys);

    // fused window attention (branches 0 + 1)
    win_attn_kernel<<<4608, 256, 0, stream>>>(fq4, xpk, xpv, lsc, ys);

    axial_row_kernel<<<dim3(120, 8), 256, 0, stream>>>(
        fq4 + 64 * PP, xpk + 64 * PP, xpv + 64 * PP, lrlsc, v1);
    transpose3<<<dim3(15, 15, 8), 256, 0, stream>>>(
        xpk + 64 * PP, fq4 + 64 * PP, v1, knT, qnT, v1T);
    axial_col_kernel<<<960, 256, 0, stream>>>(knT, qnT, v1T, lrlsc, ys);

    conv3x3_mfma<96, 2, 0><<<1368, 256, 0, stream>>>(ys, wtf_o, b_out, out, nullptr,
                                                     nullptr, nullptr);
}

// Round 4
// 293.208 us; speedup vs baseline: 1.0856x; 1.0288x over previous
//
#include <hip/hip_runtime.h>
#include <math.h>

#define HH 240
#define WW 240
#define PP (HH * WW)
#define PW 242              // padded height/width for conv input
#define LOG_MAX_C 4.605170185988091f  // log(100)
#define LOG2E 1.442695040888963f

typedef __bf16 bf16x8 __attribute__((ext_vector_type(8)));
typedef float  f32x4  __attribute__((ext_vector_type(4)));

// native v_exp_f32 (2^x) — NOT __exp2f (glibc macro collision on gfx950 build)
#define EXP2F(x) __builtin_amdgcn_exp2f(x)

// ===========================================================================
// Layouts:
//  xs  [row][icb][px][32]      bf16  — conv B-fragment native (r7-verified)
//  wtf [tap][ocb][icb][512]    bf16  — conv A-fragment native
//  xpk [b*8+h][y][x][4]        fp32  — conv_in K output, PRE-NORMALIZED k-hat
//  xpv [b*8+h][y][x][4]        fp32  — conv_in V output (raw)
//  fq4 [b*8+h][y][x][4]        fp32  — conv_f Q output, PRE-SCALED
//                                      q-hat * exp(min(ls,LOGMAX)) * LOG2E
//  v1      [h][y][x][4]        fp32  — axial_row output (only export)
//  knT/qnT/v1T [h][x][y][4]    fp32  — transpose3 of (xpk b2, fq4 b2, v1)
// History:
//  r10: axial 128x2q -> 256x1q: 52 -> 45.5 us (occupancy 22->44%).
//  r11: s_load scalar-pipe k/v FAILED (318 us): in-loop lgkmcnt(0) serializes
//       on ~200cy scalar latency. KEPT: conv-epilogue pre-norm K / pre-scale Q.
//  r12: axial 2 rows/block + 2 q/thread: axials now <43 us (off top-5).
//  r13: conv3x3 is top (43.6 us, MfmaUtil 16%, VALUBusy 13% — latency-bound).
//       xs (11.2 MB) > 4 MB XCD-L2; default round-robin dispatch scatters
//       adjacent xy-tiles across XCDs -> L2 working set = whole xs -> b-loads
//       hit L3 (~500-900cy) and stall. Fix: XCD-contiguous bid swizzle
//       (bid = (b&7)*171 + b>>3): each XCD owns a ~30-row band (~1.5 MB)
//       -> b-loads become L2 hits (~200cy) -> issue-bound.
// ===========================================================================

__global__ __launch_bounds__(256) void to_xs_pad(
    const float* __restrict__ in, __bf16* __restrict__ xs)
{
    const int p = blockIdx.x * 256 + threadIdx.x;
    if (p >= PW * PW) return;
    const int row = p / PW, px = p % PW;
    const bool border = (row == 0 || row == PW - 1 || px == 0 || px == PW - 1);
    union { __bf16 h[32]; uint4 u[4]; } pk;
#pragma unroll
    for (int icb = 0; icb < 3; ++icb) {
        uint4* op = (uint4*)(xs + (((size_t)row * 3 + icb) * PW + px) * 32);
        if (border) {
#pragma unroll
            for (int b = 0; b < 4; ++b) op[b] = make_uint4(0, 0, 0, 0);
        } else {
            const float* ip = in + (size_t)(icb * 32) * PP + (row - 1) * WW + (px - 1);
#pragma unroll
            for (int j = 0; j < 32; ++j) pk.h[j] = (__bf16)ip[(size_t)j * PP];
#pragma unroll
            for (int b = 0; b < 4; ++b) op[b] = pk.u[b];
        }
    }
}

__global__ __launch_bounds__(256) void wt_frag(
    const float* __restrict__ w, __bf16* __restrict__ wtf, int OC)
{
    const int t = blockIdx.x * 256 + threadIdx.x;
    if (t >= 9 * (OC / 16) * 3 * 64) return;
    const int lane = t & 63;
    const int rest = t >> 6;
    const int icb  = rest % 3;
    const int to   = rest / 3;
    const int ocb  = to % (OC / 16);
    const int tap  = to / (OC / 16);
    const int ln = lane & 15, quad = lane >> 4;
    const int oc  = ocb * 16 + ln;
    const int ic0 = icb * 32 + quad * 8;
    __bf16* op = wtf + (size_t)rest * 512 + lane * 8;
#pragma unroll
    for (int d = 0; d < 8; ++d)
        op[d] = (__bf16)w[(size_t)(oc * 96 + ic0 + d) * 9 + tap];
}

__global__ __launch_bounds__(256) void zero_border_xs(__bf16* __restrict__ ys)
{
    const int idx = blockIdx.x * 256 + threadIdx.x;
    if (idx >= 4 * PW) return;
    const int g = idx / PW, i = idx % PW;
    int row, px;
    if (g == 0)      { row = 0;      px = i; }
    else if (g == 1) { row = PW - 1; px = i; }
    else if (g == 2) { row = i;      px = 0; }
    else             { row = i;      px = PW - 1; }
#pragma unroll
    for (int icb = 0; icb < 3; ++icb) {
        uint4* op = (uint4*)(ys + (((size_t)row * 3 + icb) * PW + px) * 32);
#pragma unroll
        for (int b = 0; b < 4; ++b) op[b] = make_uint4(0, 0, 0, 0);
    }
}

// ---------------------------------------------------------------------------
// Implicit-GEMM 3x3 conv on MFMA (r7-verified core). EPI selects epilogue:
//  0: NCHW fp32 (conv_out)
//  1: xpk/xpv f32x4 (conv_in) — K side (out0) stored PRE-NORMALIZED
//  2: fq4 (conv_f) — stored PRE-SCALED: q-hat * scale_h * LOG2E
// r13: XCD-contiguous bid swizzle (grid 1368 = 8 * 171): each XCD gets a
// contiguous run of xy tiles -> its xs band (~1.5 MB) is L2-resident.
// ---------------------------------------------------------------------------
template <int OC, int MT, int EPI>
__global__ __launch_bounds__(256) void conv3x3_mfma(
    const __bf16* __restrict__ xs, const __bf16* __restrict__ wtf,
    const float* __restrict__ bias, float* __restrict__ out0,
    float* __restrict__ out1, const float* __restrict__ lsc,
    const float* __restrict__ lrlsc)
{
    const int bid0  = blockIdx.x;
    const int bid   = (bid0 & 7) * 171 + (bid0 >> 3);   // XCD-contiguous
    const int group = bid / 24;
    const int w24   = bid % 24;
    const int z     = w24 >> 3;
    const int xy    = group * 8 + (w24 & 7);
    if (xy >= 450) return;
    const int x0  = (xy % 15) * 16;
    const int y0  = (xy / 15) * 8;
    const int oc0 = z * (MT * 16);
    const int ocb0 = oc0 / 16;

    const int wave = threadIdx.x >> 6;
    const int lane = threadIdx.x & 63;
    const int ln   = lane & 15;
    const int quad = lane >> 4;
    const int r0   = y0 + wave * 2;

    f32x4 acc[MT][2] = {};
    bf16x8 a[2][MT], b[2][2];

    const __bf16* abase = wtf + (size_t)lane * 8;
    const __bf16* bbase = xs + (size_t)ln * 32 + quad * 8;

#define LOAD_CHUNK(c, buf)                                                    \
    {                                                                         \
        const int tap_ = (c) / 3, icb_ = (c) % 3;                             \
        const int dy_ = tap_ / 3, dx_ = tap_ % 3;                             \
        const __bf16* ap_ = abase + (size_t)((tap_ * (OC / 16) + ocb0) * 3 + icb_) * 512; \
        _Pragma("unroll")                                                     \
        for (int mi = 0; mi < MT; ++mi)                                       \
            a[buf][mi] = *(const bf16x8*)(ap_ + (size_t)mi * 1536);           \
        _Pragma("unroll")                                                     \
        for (int ni = 0; ni < 2; ++ni)                                        \
            b[buf][ni] = *(const bf16x8*)(bbase +                             \
                (((size_t)(r0 + ni + dy_) * 3 + icb_) * PW + x0 + dx_) * 32); \
    }

    LOAD_CHUNK(0, 0)
#pragma unroll
    for (int c = 0; c < 27; ++c) {
        const int cur = c & 1, nxt = cur ^ 1;
        if (c < 26) LOAD_CHUNK(c + 1, nxt)
#pragma unroll
        for (int mi = 0; mi < MT; ++mi)
#pragma unroll
            for (int ni = 0; ni < 2; ++ni)
                acc[mi][ni] = __builtin_amdgcn_mfma_f32_16x16x32_bf16(
                    a[cur][mi], b[cur][ni], acc[mi][ni], 0, 0, 0);
    }
#undef LOAD_CHUNK

    if constexpr (EPI == 0) {
#pragma unroll
        for (int mi = 0; mi < MT; ++mi) {
#pragma unroll
            for (int r = 0; r < 4; ++r) {
                const int oc = oc0 + mi * 16 + quad * 4 + r;
                const float bv = bias[oc];
#pragma unroll
                for (int ni = 0; ni < 2; ++ni)
                    out0[(size_t)oc * PP + (r0 + ni) * WW + x0 + ln] = acc[mi][ni][r] + bv;
            }
        }
    } else if constexpr (EPI == 1) {
#pragma unroll
        for (int mi = 0; mi < MT; ++mi) {
            const f32x4 bv = *(const f32x4*)(bias + oc0 + mi * 16 + quad * 4);
            float* dst = (mi >> 1) ? out1 : out0;
            const int h8 = z * 8 + (mi & 1) * 4 + quad;
#pragma unroll
            for (int ni = 0; ni < 2; ++ni) {
                f32x4 o = acc[mi][ni] + bv;
                if ((mi >> 1) == 0) {  // K side: store k-hat
                    const float ksq = o[0]*o[0] + o[1]*o[1] + o[2]*o[2] + o[3]*o[3];
                    o *= 1.0f / fmaxf(sqrtf(ksq), 1e-12f);
                }
                *(f32x4*)(dst + (((size_t)h8 * 240 + r0 + ni) * 240 + x0 + ln) * 4) = o;
            }
        }
    } else {
#pragma unroll
        for (int mi = 0; mi < MT; ++mi) {
            const f32x4 bv = *(const f32x4*)(bias + oc0 + mi * 16 + quad * 4);
            const int h8 = z * 8 + mi * 4 + quad;
            const int br = h8 >> 3, hh = h8 & 7;
            const float ls = (br == 2) ? lrlsc[hh] : lsc[hh];
            const float qsc = __expf(fminf(ls, LOG_MAX_C)) * LOG2E;
#pragma unroll
            for (int ni = 0; ni < 2; ++ni) {
                f32x4 o = acc[mi][ni] + bv;
                const float qsq = o[0]*o[0] + o[1]*o[1] + o[2]*o[2] + o[3]*o[3];
                o *= qsc / fmaxf(sqrtf(qsq), 1e-12f);
                *(f32x4*)(out0 + (((size_t)h8 * 240 + r0 + ni) * 240 + x0 + ln) * 4) = o;
            }
        }
    }
}

// ---------------------------------------------------------------------------
// Window cosine attention, branches 0+1 FUSED in one launch (4608 blocks).
// br = bid/2304 selects branch (channel slice, shifts, icb); 2304%8==0 keeps
// the XCD swizzle property on the low bits. Fixed-max single-pass softmax.
// r11: inputs arrive pre-normalized (k-hat) / pre-scaled (q-hat*qs).
// ---------------------------------------------------------------------------
__global__ __launch_bounds__(256) void win_attn_kernel(
    const float* __restrict__ fq4, const float* __restrict__ xpk,
    const float* __restrict__ xpv, const float* __restrict__ lsc,
    __bf16* __restrict__ ys)
{
    __shared__ f32x4 ks[8][25];
    __shared__ f32x4 vs[8][25];
    const int bid = blockIdx.x;
    const int br  = bid / 2304;          // 0: plain, 1: shifted
    const int id  = bid % 2304;
    const int wi  = id / 288;
    const int g   = id % 288;
    const int wy  = g / 6;
    const int wx  = (g % 6) * 8 + wi;
    const int gshift = br * 3, sshift = br * 2;
    const size_t choff = (size_t)br * 32 * PP;
    const int t = threadIdx.x;
    const int h = t / 25, i = t % 25;
    f32x4 qn = {0, 0, 0, 0};
    float negM2 = 0.f;
    int oy = 0, ox = 0;

    if (t < 200) {
        const int y = (wy * 5 + i / 5 + gshift) % HH;
        const int x = (wx * 5 + i % 5 + gshift) % WW;
        const size_t p4 = choff + (((size_t)h * 240 + y) * 240 + x) * 4;
        qn = *(const f32x4*)(fq4 + p4);              // pre-scaled q
        ks[h][i] = *(const f32x4*)(xpk + p4);        // pre-normalized k
        vs[h][i] = *(const f32x4*)(xpv + p4);
        const float scale = __expf(fminf(lsc[h], LOG_MAX_C));
        negM2 = -scale * LOG2E;
        oy = (wy * 5 + i / 5 + sshift) % HH;
        ox = (wx * 5 + i % 5 + sshift) % WW;
    }
    __syncthreads();
    if (t < 200) {
        float l = 0.f;
        f32x4 acc = {0, 0, 0, 0};
#pragma unroll
        for (int j = 0; j < 25; ++j) {
            const f32x4 kk = ks[h][j];
            const float s = fmaf(qn[0], kk[0],
                            fmaf(qn[1], kk[1],
                            fmaf(qn[2], kk[2],
                            fmaf(qn[3], kk[3], negM2))));
            const float p = EXP2F(s);
            l += p;
            acc += vs[h][j] * p;
        }
        const float linv = 1.0f / l;
        union { __bf16 h4[4]; uint2 u; } o;
#pragma unroll
        for (int d = 0; d < 4; ++d) o.h4[d] = (__bf16)(acc[d] * linv);
        *(uint2*)(ys + (((size_t)(oy + 1) * 3 + br) * PW + ox + 1) * 32 + h * 4) = o.u;
    }
}

// ---------------------------------------------------------------------------
// Axial row attention (over w). r12: 2 rows/block, 2 queries/thread, 256thr.
// Waves 0,1 -> row y0; waves 2,3 -> row y0+1 (half = t>>7, wave-aligned so
// ks[half][j] broadcasts stay wave-uniform). Each ks/vs broadcast pair feeds
// 36 VALU-cycles (18 instrs x 2cy) -> VALU-bound, not LDS-return-bound.
// Inputs pre-normalized/pre-scaled by conv epilogues; only export is v1.
// ---------------------------------------------------------------------------
__global__ __launch_bounds__(256) void axial_row_kernel(
    const float* __restrict__ fq4b, const float* __restrict__ xpkb,
    const float* __restrict__ xpvb, const float* __restrict__ lsc,
    float* __restrict__ v1)
{
    __shared__ f32x4 ks[2][240];
    __shared__ f32x4 vs[2][240];
    const int t = threadIdx.x;
    const int half = t >> 7, tl = t & 127;
    const int y = blockIdx.x * 2 + half, h = blockIdx.y;

    const float scale = __expf(fminf(lsc[h], LOG_MAX_C));
    const float negM2 = -scale * LOG2E;
    const size_t rowb = ((size_t)h * 240 + y) * 240;
    f32x4 qreg[2] = {};

    if (tl < 120) {
#pragma unroll
        for (int s = 0; s < 2; ++s) {
            const int i = tl + s * 120;
            const size_t p4 = (rowb + i) * 4;
            ks[half][i] = *(const f32x4*)(xpkb + p4);
            vs[half][i] = *(const f32x4*)(xpvb + p4);
            qreg[s] = *(const f32x4*)(fq4b + p4);
        }
    }
    __syncthreads();
    if (tl < 120) {
        float l0 = 0.f, l1 = 0.f;
        f32x4 a0 = {0, 0, 0, 0}, a1 = {0, 0, 0, 0};
#pragma unroll 4
        for (int j = 0; j < 240; ++j) {
            const f32x4 kk = ks[half][j];
            const f32x4 vv = vs[half][j];
            const float s0 = fmaf(qreg[0][0], kk[0],
                             fmaf(qreg[0][1], kk[1],
                             fmaf(qreg[0][2], kk[2],
                             fmaf(qreg[0][3], kk[3], negM2))));
            const float s1 = fmaf(qreg[1][0], kk[0],
                             fmaf(qreg[1][1], kk[1],
                             fmaf(qreg[1][2], kk[2],
                             fmaf(qreg[1][3], kk[3], negM2))));
            const float p0 = EXP2F(s0);
            const float p1 = EXP2F(s1);
            l0 += p0; l1 += p1;
            a0 += vv * p0;
            a1 += vv * p1;
        }
        *(f32x4*)(v1 + (rowb + tl) * 4) = a0 * (1.0f / l0);
        *(f32x4*)(v1 + (rowb + tl + 120) * 4) = a1 * (1.0f / l1);
    }
}

// ---------------------------------------------------------------------------
// LDS-tiled (y,x)-transpose of 3 tensors [8][240][240][4] f32.
// 16x16 f32x4 tiles, 17-padded rows (2-way LDS aliasing only = free, m136).
// Sources: (xpk b2 = k-hat, fq4 b2 = q-hat*qs, v1).
// ---------------------------------------------------------------------------
__global__ __launch_bounds__(256) void transpose3(
    const float* __restrict__ a0, const float* __restrict__ a1,
    const float* __restrict__ a2, float* __restrict__ t0,
    float* __restrict__ t1, float* __restrict__ t2)
{
    __shared__ f32x4 tile[16][17];
    const int t = threadIdx.x, ty = t >> 4, tx = t & 15;
    const int h = blockIdx.z, y0 = blockIdx.y * 16, x0 = blockIdx.x * 16;
    const size_t rd = (((size_t)h * 240 + y0 + ty) * 240 + x0 + tx) * 4;
    const size_t wr = (((size_t)h * 240 + x0 + ty) * 240 + y0 + tx) * 4;
    const float* srcs[3] = {a0, a1, a2};
    float* dsts[3] = {t0, t1, t2};
#pragma unroll
    for (int n = 0; n < 3; ++n) {
        tile[ty][tx] = *(const f32x4*)(srcs[n] + rd);
        __syncthreads();
        *(f32x4*)(dsts[n] + wr) = tile[tx][ty];
        __syncthreads();
    }
}

// ---------------------------------------------------------------------------
// Axial column attention (over h). r12: same 2-cols/block, 2q/thread
// structure as axial_row, reading the transposed exports (contiguous in j).
// ---------------------------------------------------------------------------
__global__ __launch_bounds__(256) void axial_col_kernel(
    const float* __restrict__ knT, const float* __restrict__ qnT,
    const float* __restrict__ v1T, const float* __restrict__ lsc,
    __bf16* __restrict__ ys)
{
    __shared__ f32x4 ks[2][240];
    __shared__ f32x4 vs[2][240];
    const int bid = blockIdx.x;
    const int wi  = bid / 120;           // 0..7
    const int g   = bid % 120;
    const int h   = g % 8;
    const int xc  = g / 8;               // 0..14
    const int t = threadIdx.x;
    const int half = t >> 7, tl = t & 127;
    const int x = xc * 16 + wi * 2 + half;

    const float scale = __expf(fminf(lsc[h], LOG_MAX_C));
    const float negM2 = -scale * LOG2E;
    const size_t rowb = ((size_t)h * 240 + x) * 240;
    f32x4 qreg[2] = {};

    if (tl < 120) {
#pragma unroll
        for (int s = 0; s < 2; ++s) {
            const int i = tl + s * 120;
            const size_t pT = (rowb + i) * 4;
            ks[half][i] = *(const f32x4*)(knT + pT);
            vs[half][i] = *(const f32x4*)(v1T + pT);
            qreg[s] = *(const f32x4*)(qnT + pT);
        }
    }
    __syncthreads();
    if (tl < 120) {
        float l0 = 0.f, l1 = 0.f;
        f32x4 a0 = {0, 0, 0, 0}, a1 = {0, 0, 0, 0};
#pragma unroll 4
        for (int j = 0; j < 240; ++j) {
            const f32x4 kk = ks[half][j];
            const f32x4 vv = vs[half][j];
            const float s0 = fmaf(qreg[0][0], kk[0],
                             fmaf(qreg[0][1], kk[1],
                             fmaf(qreg[0][2], kk[2],
                             fmaf(qreg[0][3], kk[3], negM2))));
            const float s1 = fmaf(qreg[1][0], kk[0],
                             fmaf(qreg[1][1], kk[1],
                             fmaf(qreg[1][2], kk[2],
                             fmaf(qreg[1][3], kk[3], negM2))));
            const float p0 = EXP2F(s0);
            const float p1 = EXP2F(s1);
            l0 += p0; l1 += p1;
            a0 += vv * p0;
            a1 += vv * p1;
        }
#pragma unroll
        for (int s = 0; s < 2; ++s) {
            const f32x4 o4 = s ? a1 * (1.0f / l1) : a0 * (1.0f / l0);
            const int i = tl + s * 120;
            union { __bf16 h4[4]; uint2 u; } o;
#pragma unroll
            for (int d = 0; d < 4; ++d) o.h4[d] = (__bf16)o4[d];
            *(uint2*)(ys + (((size_t)(i + 1) * 3 + 2) * PW + x + 1) * 32 + h * 4) = o.u;
        }
    }
}

// ---------------------------------------------------------------------------
// Pipeline. Workspace (fp32 units):
//   xpk 96PP | xpv 96PP | fq4 96PP | xs/ys bf16 | wtf_in | wtf_f | wtf_o
// Aliases (b0/b1 slices of xpk/xpv/fq4 are dead after fused win_attn):
//   v1  = xpv b0 | knT = xpv b1 | qnT = fq4 b0 | v1T = fq4 b1
// axial_row reads only b2 slices, writes v1; transpose3 reads
// (xpk b2, fq4 b2, v1), writes *T; axial_col reads *T.
// Stream order guarantees safety.
// ---------------------------------------------------------------------------
extern "C" void kernel_launch(void* const* d_in, const int* in_sizes, int n_in,
                              void* d_out, int out_size, void* d_ws, size_t ws_size,
                              hipStream_t stream)
{
    const float* x     = (const float*)d_in[0];
    const float* w_in  = (const float*)d_in[1];
    const float* b_in  = (const float*)d_in[2];
    const float* w_f   = (const float*)d_in[3];
    const float* b_f   = (const float*)d_in[4];
    const float* w_out = (const float*)d_in[5];
    const float* b_out = (const float*)d_in[6];
    const float* lsc   = (const float*)d_in[7];
    const float* lrlsc = (const float*)d_in[8];
    float* out = (float*)d_out;

    float* ws  = (float*)d_ws;
    float* xpk = ws;                   // 96*PP
    float* xpv = xpk + 96 * PP;        // 96*PP
    float* fq4 = xpv + 96 * PP;        // 96*PP
    __bf16* xs     = (__bf16*)(fq4 + 96 * PP);            // 242*3*242*32 bf16
    __bf16* wtf_in = xs + (size_t)PW * 3 * PW * 32;
    __bf16* wtf_f  = wtf_in + 9 * 12 * 3 * 512;
    __bf16* wtf_o  = wtf_f + 9 * 6 * 3 * 512;
    __bf16* ys     = xs;               // alias: xs dead after conv_in/conv_f

    float* v1  = xpv;                  // b0, dead after fused win_attn
    float* knT = xpv + 32 * PP;        // b1
    float* qnT = fq4;                  // b0
    float* v1T = fq4 + 32 * PP;        // b1

    wt_frag<<<(9 * 12 * 3 * 64 + 255) / 256, 256, 0, stream>>>(w_in, wtf_in, 192);
    wt_frag<<<(9 * 6 * 3 * 64 + 255) / 256, 256, 0, stream>>>(w_f, wtf_f, 96);
    wt_frag<<<(9 * 6 * 3 * 64 + 255) / 256, 256, 0, stream>>>(w_out, wtf_o, 96);
    to_xs_pad<<<(PW * PW + 255) / 256, 256, 0, stream>>>(x, xs);

    conv3x3_mfma<192, 4, 1><<<1368, 256, 0, stream>>>(xs, wtf_in, b_in, xpk, xpv,
                                                      nullptr, nullptr);
    conv3x3_mfma<96, 2, 2><<<1368, 256, 0, stream>>>(xs, wtf_f, b_f, fq4, nullptr,
                                                     lsc, lrlsc);

    zero_border_xs<<<(4 * PW + 255) / 256, 256, 0, stream>>>(ys);

    // fused window attention (branches 0 + 1)
    win_attn_kernel<<<4608, 256, 0, stream>>>(fq4, xpk, xpv, lsc, ys);

    axial_row_kernel<<<dim3(120, 8), 256, 0, stream>>>(
        fq4 + 64 * PP, xpk + 64 * PP, xpv + 64 * PP, lrlsc, v1);
    transpose3<<<dim3(15, 15, 8), 256, 0, stream>>>(
        xpk + 64 * PP, fq4 + 64 * PP, v1, knT, qnT, v1T);
    axial_col_kernel<<<960, 256, 0, stream>>>(knT, qnT, v1T, lrlsc, ys);

    conv3x3_mfma<96, 2, 0><<<1368, 256, 0, stream>>>(ys, wtf_o, b_out, out, nullptr,
                                                     nullptr, nullptr);
}